// Round 1
// baseline (228.958 us; speedup 1.0000x reference)
//
#include <hip/hip_runtime.h>
#include <hip/hip_bf16.h>

// Shapes (fixed by the problem)
#define BATCH 8
#define SEQ   2048
#define DM    768
#define DD    64   // DK == DV == 64

typedef __bf16 bf16x8 __attribute__((ext_vector_type(8)));
typedef float  f32x4  __attribute__((ext_vector_type(4)));
typedef short  short8 __attribute__((ext_vector_type(8)));
typedef short  short4v __attribute__((ext_vector_type(4)));

#define MFMA16(a, b, c) __builtin_amdgcn_mfma_f32_16x16x32_bf16((a), (b), (c), 0, 0, 0)

__device__ __forceinline__ short f2bf(float x) {
    unsigned u = __builtin_bit_cast(unsigned, x);
    u = (u + 0x7fffu + ((u >> 16) & 1u)) >> 16;   // round-to-nearest-even
    return (short)u;
}
__device__ __forceinline__ float bf2f(short s) {
    unsigned u = ((unsigned)(unsigned short)s) << 16;
    return __builtin_bit_cast(float, u);
}

// ---------------------------------------------------------------------------
// Kernel 1: W [768][64] f32  ->  Wt [3][64][768] bf16 (transposed, n-major)
// ---------------------------------------------------------------------------
__global__ void prep_w_kernel(const float* __restrict__ Wq, const float* __restrict__ Wk,
                              const float* __restrict__ Wv, short* __restrict__ Wt) {
    int idx = blockIdx.x * 256 + threadIdx.x;   // 3*768*64 = 147456 total
    if (idx >= 3 * DM * DD) return;
    int m = idx / (DM * DD);
    int r = (idx % (DM * DD)) / DD;   // k in [0,768)
    int c = idx % DD;                 // n in [0,64)
    const float* W = (m == 0) ? Wq : (m == 1) ? Wk : Wv;
    Wt[m * DM * DD + c * DM + r] = f2bf(W[r * DD + c]);
}

// ---------------------------------------------------------------------------
// Kernel 2: Q = (x1 @ Wq + bq) * 1/8   -> bf16 [16384][64] row-major
// 64 rows/block, 4 waves x (16 rows x 64 cols), K-steps of 32, mfma 16x16x32
// LDS rows padded to 40 shorts (2-way bank aliasing only).
// ---------------------------------------------------------------------------
__global__ __launch_bounds__(256) void proj_q_kernel(
        const float* __restrict__ x, const short* __restrict__ Wt,
        const float* __restrict__ bias, short* __restrict__ out, float scale) {
    __shared__ __align__(16) short xl[64 * 40];
    __shared__ __align__(16) short wl[64 * 40];
    const int tid  = threadIdx.x;
    const int wave = tid >> 6, lane = tid & 63, quad = lane >> 4, l15 = lane & 15;
    const int r0   = blockIdx.x * 64;
    const int trow = tid >> 2, tc = tid & 3;
    f32x4 acc[4] = {};
    for (int k0 = 0; k0 < DM; k0 += 32) {
        __syncthreads();
        const float* xp = x + (size_t)(r0 + trow) * DM + k0 + tc * 8;
        float4 a = *(const float4*)xp;
        float4 b = *(const float4*)(xp + 4);
        short8 xs;
        xs[0] = f2bf(a.x); xs[1] = f2bf(a.y); xs[2] = f2bf(a.z); xs[3] = f2bf(a.w);
        xs[4] = f2bf(b.x); xs[5] = f2bf(b.y); xs[6] = f2bf(b.z); xs[7] = f2bf(b.w);
        *(short8*)&xl[trow * 40 + tc * 8] = xs;
        *(short8*)&wl[trow * 40 + tc * 8] = *(const short8*)(Wt + trow * DM + k0 + tc * 8);
        __syncthreads();
        bf16x8 af = *(const bf16x8*)&xl[(wave * 16 + l15) * 40 + quad * 8];
#pragma unroll
        for (int tn = 0; tn < 4; tn++) {
            bf16x8 bfr = *(const bf16x8*)&wl[(tn * 16 + l15) * 40 + quad * 8];
            acc[tn] = MFMA16(af, bfr, acc[tn]);
        }
    }
#pragma unroll
    for (int tn = 0; tn < 4; tn++) {
        int v = tn * 16 + l15;
        float bv = bias[v];
#pragma unroll
        for (int r = 0; r < 4; r++) {
            int row = r0 + wave * 16 + quad * 4 + r;
            out[(size_t)row * DD + v] = f2bf((acc[tn][r] + bv) * scale);
        }
    }
}

// ---------------------------------------------------------------------------
// Kernel 3: K = x2@Wk + bk  -> bf16 [16384][64];  Vt = (x2@Wv + bv)^T per
// batch -> bf16 [8][64][2048]. Fused so x2 is read from HBM once.
// ---------------------------------------------------------------------------
__global__ __launch_bounds__(256) void proj_kv_kernel(
        const float* __restrict__ x, const short* __restrict__ Wtk,
        const short* __restrict__ Wtv, const float* __restrict__ bk,
        const float* __restrict__ bv, short* __restrict__ Kout,
        short* __restrict__ Vtout) {
    __shared__ __align__(16) short xl[64 * 40];
    __shared__ __align__(16) short wkl[64 * 40];
    __shared__ __align__(16) short wvl[64 * 40];
    const int tid  = threadIdx.x;
    const int wave = tid >> 6, lane = tid & 63, quad = lane >> 4, l15 = lane & 15;
    const int r0   = blockIdx.x * 64;
    const int trow = tid >> 2, tc = tid & 3;
    f32x4 acck[4] = {}, accv[4] = {};
    for (int k0 = 0; k0 < DM; k0 += 32) {
        __syncthreads();
        const float* xp = x + (size_t)(r0 + trow) * DM + k0 + tc * 8;
        float4 a = *(const float4*)xp;
        float4 b = *(const float4*)(xp + 4);
        short8 xs;
        xs[0] = f2bf(a.x); xs[1] = f2bf(a.y); xs[2] = f2bf(a.z); xs[3] = f2bf(a.w);
        xs[4] = f2bf(b.x); xs[5] = f2bf(b.y); xs[6] = f2bf(b.z); xs[7] = f2bf(b.w);
        *(short8*)&xl[trow * 40 + tc * 8] = xs;
        *(short8*)&wkl[trow * 40 + tc * 8] = *(const short8*)(Wtk + trow * DM + k0 + tc * 8);
        *(short8*)&wvl[trow * 40 + tc * 8] = *(const short8*)(Wtv + trow * DM + k0 + tc * 8);
        __syncthreads();
        bf16x8 af = *(const bf16x8*)&xl[(wave * 16 + l15) * 40 + quad * 8];
#pragma unroll
        for (int tn = 0; tn < 4; tn++) {
            bf16x8 bk8 = *(const bf16x8*)&wkl[(tn * 16 + l15) * 40 + quad * 8];
            acck[tn] = MFMA16(af, bk8, acck[tn]);
            bf16x8 bv8 = *(const bf16x8*)&wvl[(tn * 16 + l15) * 40 + quad * 8];
            accv[tn] = MFMA16(af, bv8, accv[tn]);
        }
    }
    // K: row-major store
#pragma unroll
    for (int tn = 0; tn < 4; tn++) {
        int v = tn * 16 + l15;
        float bb = bk[v];
#pragma unroll
        for (int r = 0; r < 4; r++) {
            int row = r0 + wave * 16 + quad * 4 + r;
            Kout[(size_t)row * DD + v] = f2bf(acck[tn][r] + bb);
        }
    }
    // Vt: transposed store [b][v][s], 4 consecutive s per lane -> 8B packed
    const int b = r0 / SEQ;
    const int sbase = (r0 % SEQ) + wave * 16 + quad * 4;
#pragma unroll
    for (int tn = 0; tn < 4; tn++) {
        int v = tn * 16 + l15;
        float bb = bv[v];
        short4v pk;
#pragma unroll
        for (int r = 0; r < 4; r++) pk[r] = f2bf(accv[tn][r] + bb);
        *(short4v*)(Vtout + ((size_t)b * DD + v) * SEQ + sbase) = pk;
    }
}

// ---------------------------------------------------------------------------
// Kernel 4: C[b][v] = sum_s V[b][s][v]  (row sums of Vt), f32
// ---------------------------------------------------------------------------
__global__ void csum_kernel(const short* __restrict__ Vt, float* __restrict__ C) {
    int row  = blockIdx.x;      // b*64 + v, 512 rows
    int lane = threadIdx.x;     // 64
    const short* p = Vt + (size_t)row * SEQ;
    float s = 0.f;
#pragma unroll
    for (int c = 0; c < 4; c++) {
        short8 v = *(const short8*)(p + c * 512 + lane * 8);
#pragma unroll
        for (int j = 0; j < 8; j++) s += bf2f(v[j]);
    }
#pragma unroll
    for (int m = 1; m < 64; m <<= 1) s += __shfl_xor(s, m);
    if (lane == 0) C[row] = s;
}

// ---------------------------------------------------------------------------
// Kernel 5: flash attention + reverse-weight transform + LayerNorm
// grid (32 q-tiles, 8 batches), block 256 = 4 waves x 16 q-rows.
// Single-pass softmax (scores bounded, no running max needed):
//   y = sum_s e^{z} V / sum_s e^{z};  attn = (C - y)/2047;  out = LN(attn)
// ---------------------------------------------------------------------------
__global__ __launch_bounds__(256) void flash_kernel(
        const short* __restrict__ Q, const short* __restrict__ K,
        const short* __restrict__ Vt, const float* __restrict__ C,
        const float* __restrict__ gamma, const float* __restrict__ beta,
        float* __restrict__ out) {
    __shared__ __align__(16) short kl[64 * 72];       // K tile [s][dk], pad->72
    __shared__ __align__(16) short vl[64 * 72];       // Vt tile [v][s], pad->72
    __shared__ __align__(16) short pb[4][16 * 72];    // per-wave P transpose buf
    const int tid  = threadIdx.x;
    const int wave = tid >> 6, lane = tid & 63, quad = lane >> 4, l15 = lane & 15;
    const int b = blockIdx.y, q0 = blockIdx.x * 64;

    // Q fragments (A-operand): row = wave*16 + l15, k = kc*32 + quad*8 + j
    const short* Qp = Q + ((size_t)(b * SEQ + q0) + wave * 16 + l15) * DD;
    bf16x8 qa0 = *(const bf16x8*)(Qp + quad * 8);
    bf16x8 qa1 = *(const bf16x8*)(Qp + 32 + quad * 8);

    const short* Kb = K  + (size_t)b * SEQ * DD;
    const short* Vb = Vt + (size_t)b * DD * SEQ;
    f32x4 y[4] = {};
    float den[4] = {0.f, 0.f, 0.f, 0.f};
    const int trow = tid >> 2, tcb = (tid & 3) * 2;
    short* pw = &pb[wave][0];

    for (int s0 = 0; s0 < SEQ; s0 += 64) {
        __syncthreads();
        const short* kp = Kb + (size_t)(s0 + trow) * DD + tcb * 8;
        *(short8*)&kl[trow * 72 + tcb * 8]     = *(const short8*)kp;
        *(short8*)&kl[trow * 72 + tcb * 8 + 8] = *(const short8*)(kp + 8);
        const short* vp = Vb + (size_t)trow * SEQ + s0 + tcb * 8;
        *(short8*)&vl[trow * 72 + tcb * 8]     = *(const short8*)vp;
        *(short8*)&vl[trow * 72 + tcb * 8 + 8] = *(const short8*)(vp + 8);
        __syncthreads();
        // QK^T: S-tile 16q x 64s per wave; C-layout: col(s)=l15, row(q)=quad*4+r
#pragma unroll
        for (int tn = 0; tn < 4; tn++) {
            f32x4 z = {0.f, 0.f, 0.f, 0.f};
            z = MFMA16(qa0, *(const bf16x8*)&kl[(tn * 16 + l15) * 72 + quad * 8], z);
            z = MFMA16(qa1, *(const bf16x8*)&kl[(tn * 16 + l15) * 72 + 32 + quad * 8], z);
#pragma unroll
            for (int r = 0; r < 4; r++) {
                float p = __expf(z[r]);
                den[r] += p;
                pw[(quad * 4 + r) * 72 + tn * 16 + l15] = f2bf(p);  // transpose to A-layout
            }
        }
        // PV: A = P from pb (A-layout), B = Vt tile
#pragma unroll
        for (int kc = 0; kc < 2; kc++) {
            bf16x8 pa = *(const bf16x8*)&pw[l15 * 72 + kc * 32 + quad * 8];
#pragma unroll
            for (int tn = 0; tn < 4; tn++) {
                bf16x8 vb8 = *(const bf16x8*)&vl[(tn * 16 + l15) * 72 + kc * 32 + quad * 8];
                y[tn] = MFMA16(pa, vb8, y[tn]);
            }
        }
    }
    // row-sum of exp(z): reduce across the 16 lanes of each quad-group
#pragma unroll
    for (int m = 1; m < 16; m <<= 1) {
#pragma unroll
        for (int r = 0; r < 4; r++) den[r] += __shfl_xor(den[r], m);
    }
    // reverse transform + LN over v (64 values per q-row)
    float attn[4][4];
    float msum[4] = {0.f, 0.f, 0.f, 0.f}, ssum[4] = {0.f, 0.f, 0.f, 0.f};
#pragma unroll
    for (int tn = 0; tn < 4; tn++) {
        float Cv = C[b * DD + tn * 16 + l15];
#pragma unroll
        for (int r = 0; r < 4; r++) {
            float a = (Cv - y[tn][r] / den[r]) * (1.0f / (float)(SEQ - 1));
            attn[tn][r] = a;
            msum[r] += a;
            ssum[r] += a * a;
        }
    }
#pragma unroll
    for (int m = 1; m < 16; m <<= 1) {
#pragma unroll
        for (int r = 0; r < 4; r++) {
            msum[r] += __shfl_xor(msum[r], m);
            ssum[r] += __shfl_xor(ssum[r], m);
        }
    }
    float mu[4], rs[4];
#pragma unroll
    for (int r = 0; r < 4; r++) {
        mu[r] = msum[r] * (1.0f / 64.0f);
        float var = ssum[r] * (1.0f / 64.0f) - mu[r] * mu[r];
        rs[r] = rsqrtf(var + 1e-5f);
    }
    size_t obase = ((size_t)b * SEQ + q0 + wave * 16 + quad * 4) * DD;
#pragma unroll
    for (int tn = 0; tn < 4; tn++) {
        int v = tn * 16 + l15;
        float g = gamma[v], be = beta[v];
#pragma unroll
        for (int r = 0; r < 4; r++) {
            out[obase + (size_t)r * DD + v] = (attn[tn][r] - mu[r]) * rs[r] * g + be;
        }
    }
}

// ---------------------------------------------------------------------------
extern "C" void kernel_launch(void* const* d_in, const int* in_sizes, int n_in,
                              void* d_out, int out_size, void* d_ws, size_t ws_size,
                              hipStream_t stream) {
    const float* x1    = (const float*)d_in[0];
    const float* x2    = (const float*)d_in[1];
    const float* Wq    = (const float*)d_in[2];
    const float* bq    = (const float*)d_in[3];
    const float* Wk    = (const float*)d_in[4];
    const float* bk    = (const float*)d_in[5];
    const float* Wv    = (const float*)d_in[6];
    const float* bv    = (const float*)d_in[7];
    const float* gamma = (const float*)d_in[8];
    const float* beta  = (const float*)d_in[9];
    float* out = (float*)d_out;

    char* ws = (char*)d_ws;
    short* Qs  = (short*)(ws);                         // 2 MB  bf16 [16384][64] (pre-scaled 1/8)
    short* Kb  = (short*)(ws + (2ull << 20));          // 2 MB  bf16 [16384][64]
    short* Vtb = (short*)(ws + (4ull << 20));          // 2 MB  bf16 [8][64][2048]
    short* Wt  = (short*)(ws + (6ull << 20));          // 288 KB bf16 [3][64][768]
    float* Cc  = (float*)(ws + (6ull << 20) + 3 * DM * DD * 2);  // 2 KB f32 [8][64]

    prep_w_kernel<<<576, 256, 0, stream>>>(Wq, Wk, Wv, Wt);
    proj_q_kernel<<<256, 256, 0, stream>>>(x1, Wt, bq, Qs, 0.125f);
    proj_kv_kernel<<<256, 256, 0, stream>>>(x2, Wt + DM * DD, Wt + 2 * DM * DD,
                                            bk, bv, Kb, Vtb);
    csum_kernel<<<512, 64, 0, stream>>>(Vtb, Cc);
    flash_kernel<<<dim3(32, 8), 256, 0, stream>>>(Qs, Kb, Vtb, Cc, gamma, beta, out);
}

// Round 2
// 226.199 us; speedup vs baseline: 1.0122x; 1.0122x over previous
//
#include <hip/hip_runtime.h>
#include <hip/hip_bf16.h>

// Shapes (fixed by the problem)
#define BATCH 8
#define SEQ   2048
#define DM    768
#define DD    64   // DK == DV == 64
#define NSPLIT 4
#define SPLIT_S (SEQ / NSPLIT)   // 512
#define BS (BATCH * SEQ)         // 16384

typedef __bf16 bf16x8 __attribute__((ext_vector_type(8)));
typedef float  f32x4  __attribute__((ext_vector_type(4)));
typedef short  short8 __attribute__((ext_vector_type(8)));
typedef short  short4v __attribute__((ext_vector_type(4)));

#define MFMA16(a, b, c) __builtin_amdgcn_mfma_f32_16x16x32_bf16((a), (b), (c), 0, 0, 0)

__device__ __forceinline__ short f2bf(float x) {
    unsigned u = __builtin_bit_cast(unsigned, x);
    u = (u + 0x7fffu + ((u >> 16) & 1u)) >> 16;   // round-to-nearest-even
    return (short)u;
}
__device__ __forceinline__ float bf2f(short s) {
    unsigned u = ((unsigned)(unsigned short)s) << 16;
    return __builtin_bit_cast(float, u);
}

// ---------------------------------------------------------------------------
// Kernel 1: W [768][64] f32 -> Wt [3][64][768] bf16 (transposed, n-major).
// Wq is pre-scaled by 1/8 (the 1/sqrt(DK) of the attention scores).
// ---------------------------------------------------------------------------
__global__ void prep_w_kernel(const float* __restrict__ Wq, const float* __restrict__ Wk,
                              const float* __restrict__ Wv, short* __restrict__ Wt) {
    int idx = blockIdx.x * 256 + threadIdx.x;   // 3*768*64 = 147456 total
    if (idx >= 3 * DM * DD) return;
    int m = idx / (DM * DD);
    int r = (idx % (DM * DD)) / DD;   // k in [0,768)
    int c = idx % DD;                 // n in [0,64)
    const float* W = (m == 0) ? Wq : (m == 1) ? Wk : Wv;
    float scale = (m == 0) ? 0.125f : 1.0f;
    Wt[m * DM * DD + c * DM + r] = f2bf(W[r * DD + c] * scale);
}

// ---------------------------------------------------------------------------
// Kernel 2: fused projections, NO LDS / NO barriers. 1 wave per block,
// 16 rows per wave. Blocks [0,1024): Q = x1@Wq' + bq'; blocks [1024,2048):
// K = x2@Wk + bk (row-major) and Vt = (x2@Wv + bv)^T [b][v][s].
// A-frags read from x directly (float4x2 -> bf16), B-frags read from Wt in
// global (L2-resident, 16rows x 64B coalesced).
// ---------------------------------------------------------------------------
__global__ __launch_bounds__(64) void fused_proj_kernel(
        const float* __restrict__ x1, const float* __restrict__ x2,
        const short* __restrict__ Wt,
        const float* __restrict__ bq, const float* __restrict__ bk,
        const float* __restrict__ bv,
        short* __restrict__ Qs, short* __restrict__ Kb, short* __restrict__ Vtb) {
    const int lane = threadIdx.x, quad = lane >> 4, l15 = lane & 15;
    const bool is_q = blockIdx.x < 1024;
    const int r0 = (is_q ? blockIdx.x : blockIdx.x - 1024) * 16;

    const float* xp = (is_q ? x1 : x2) + (size_t)(r0 + l15) * DM + quad * 8;

    if (is_q) {
        const short* Wq_ = Wt + (size_t)(quad * 8) ;  // base offset folded below
        f32x4 acc[4] = {};
#pragma unroll 4
        for (int k0 = 0; k0 < DM; k0 += 32) {
            float4 a = *(const float4*)(xp + k0);
            float4 b2 = *(const float4*)(xp + k0 + 4);
            bf16x8 af;
            af[0] = (__bf16)a.x; af[1] = (__bf16)a.y; af[2] = (__bf16)a.z; af[3] = (__bf16)a.w;
            af[4] = (__bf16)b2.x; af[5] = (__bf16)b2.y; af[6] = (__bf16)b2.z; af[7] = (__bf16)b2.w;
#pragma unroll
            for (int tn = 0; tn < 4; tn++) {
                bf16x8 bfr = *(const bf16x8*)(Wt + (size_t)(tn * 16 + l15) * DM + k0 + quad * 8);
                acc[tn] = MFMA16(af, bfr, acc[tn]);
            }
        }
#pragma unroll
        for (int tn = 0; tn < 4; tn++) {
            int v = tn * 16 + l15;
            float bb = bq[v] * 0.125f;
#pragma unroll
            for (int r = 0; r < 4; r++) {
                int row = r0 + quad * 4 + r;
                Qs[(size_t)row * DD + v] = f2bf(acc[tn][r] + bb);
            }
        }
    } else {
        const short* Wtk = Wt + DM * DD;
        const short* Wtv = Wt + 2 * DM * DD;
        f32x4 acck[4] = {}, accv[4] = {};
#pragma unroll 4
        for (int k0 = 0; k0 < DM; k0 += 32) {
            float4 a = *(const float4*)(xp + k0);
            float4 b2 = *(const float4*)(xp + k0 + 4);
            bf16x8 af;
            af[0] = (__bf16)a.x; af[1] = (__bf16)a.y; af[2] = (__bf16)a.z; af[3] = (__bf16)a.w;
            af[4] = (__bf16)b2.x; af[5] = (__bf16)b2.y; af[6] = (__bf16)b2.z; af[7] = (__bf16)b2.w;
#pragma unroll
            for (int tn = 0; tn < 4; tn++) {
                bf16x8 bk8 = *(const bf16x8*)(Wtk + (size_t)(tn * 16 + l15) * DM + k0 + quad * 8);
                acck[tn] = MFMA16(af, bk8, acck[tn]);
                bf16x8 bv8 = *(const bf16x8*)(Wtv + (size_t)(tn * 16 + l15) * DM + k0 + quad * 8);
                accv[tn] = MFMA16(af, bv8, accv[tn]);
            }
        }
#pragma unroll
        for (int tn = 0; tn < 4; tn++) {
            int v = tn * 16 + l15;
            float bb = bk[v];
#pragma unroll
            for (int r = 0; r < 4; r++) {
                int row = r0 + quad * 4 + r;
                Kb[(size_t)row * DD + v] = f2bf(acck[tn][r] + bb);
            }
        }
        const int b = r0 / SEQ;
        const int sbase = (r0 % SEQ) + quad * 4;
#pragma unroll
        for (int tn = 0; tn < 4; tn++) {
            int v = tn * 16 + l15;
            float bb = bv[v];
            short4v pk;
#pragma unroll
            for (int r = 0; r < 4; r++) pk[r] = f2bf(accv[tn][r] + bb);
            *(short4v*)(Vtb + ((size_t)b * DD + v) * SEQ + sbase) = pk;
        }
    }
}

// ---------------------------------------------------------------------------
// Kernel 3: C[b][v] = sum_s V[b][s][v]  (row sums of Vt), f32
// ---------------------------------------------------------------------------
__global__ void csum_kernel(const short* __restrict__ Vt, float* __restrict__ C) {
    int row  = blockIdx.x;      // b*64 + v, 512 rows
    int lane = threadIdx.x;     // 64
    const short* p = Vt + (size_t)row * SEQ;
    float s = 0.f;
#pragma unroll
    for (int c = 0; c < 4; c++) {
        short8 v = *(const short8*)(p + c * 512 + lane * 8);
#pragma unroll
        for (int j = 0; j < 8; j++) s += bf2f(v[j]);
    }
#pragma unroll
    for (int m = 1; m < 64; m <<= 1) s += __shfl_xor(s, m);
    if (lane == 0) C[row] = s;
}

// ---------------------------------------------------------------------------
// Kernel 4: flash partial: grid (32 q-tiles, 8 batches, 4 s-splits).
// Each block: 64 q-rows x 512 s. Emits unnormalized Yp (bf16) and den Dp (f32).
// ---------------------------------------------------------------------------
#define PSTR 68   // pb stride: 68 shorts -> quads land on distinct bank groups
__global__ __launch_bounds__(256) void flash_kernel(
        const short* __restrict__ Q, const short* __restrict__ K,
        const short* __restrict__ Vt,
        short* __restrict__ Yp, float* __restrict__ Dp) {
    __shared__ __align__(16) short kl[64 * 72];       // K tile [s][dk], pad->72
    __shared__ __align__(16) short vl[64 * 72];       // Vt tile [v][s], pad->72
    __shared__ __align__(16) short pb[4][16 * PSTR];  // per-wave P transpose buf
    const int tid  = threadIdx.x;
    const int wave = tid >> 6, lane = tid & 63, quad = lane >> 4, l15 = lane & 15;
    const int b = blockIdx.y, q0 = blockIdx.x * 64, split = blockIdx.z;

    const short* Qp = Q + ((size_t)(b * SEQ + q0) + wave * 16 + l15) * DD;
    bf16x8 qa0 = *(const bf16x8*)(Qp + quad * 8);
    bf16x8 qa1 = *(const bf16x8*)(Qp + 32 + quad * 8);

    const short* Kb = K  + (size_t)b * SEQ * DD;
    const short* Vb = Vt + (size_t)b * DD * SEQ;
    f32x4 y[4] = {};
    float den[4] = {0.f, 0.f, 0.f, 0.f};
    const int trow = tid >> 2, tcb = (tid & 3) * 2;
    short* pw = &pb[wave][0];

    const int send = split * SPLIT_S + SPLIT_S;
    for (int s0 = split * SPLIT_S; s0 < send; s0 += 64) {
        __syncthreads();
        const short* kp = Kb + (size_t)(s0 + trow) * DD + tcb * 8;
        *(short8*)&kl[trow * 72 + tcb * 8]     = *(const short8*)kp;
        *(short8*)&kl[trow * 72 + tcb * 8 + 8] = *(const short8*)(kp + 8);
        const short* vp = Vb + (size_t)trow * SEQ + s0 + tcb * 8;
        *(short8*)&vl[trow * 72 + tcb * 8]     = *(const short8*)vp;
        *(short8*)&vl[trow * 72 + tcb * 8 + 8] = *(const short8*)(vp + 8);
        __syncthreads();
        // QK^T: 16q x 64s per wave; C-layout: col(s)=l15, row(q)=quad*4+r
#pragma unroll
        for (int tn = 0; tn < 4; tn++) {
            f32x4 z = {0.f, 0.f, 0.f, 0.f};
            z = MFMA16(qa0, *(const bf16x8*)&kl[(tn * 16 + l15) * 72 + quad * 8], z);
            z = MFMA16(qa1, *(const bf16x8*)&kl[(tn * 16 + l15) * 72 + 32 + quad * 8], z);
#pragma unroll
            for (int r = 0; r < 4; r++) {
                float p = __expf(z[r]);
                den[r] += p;
                pw[(quad * 4 + r) * PSTR + tn * 16 + l15] = f2bf(p);  // -> A-layout
            }
        }
#pragma unroll
        for (int kc = 0; kc < 2; kc++) {
            bf16x8 pa = *(const bf16x8*)&pw[l15 * PSTR + kc * 32 + quad * 8];
#pragma unroll
            for (int tn = 0; tn < 4; tn++) {
                bf16x8 vb8 = *(const bf16x8*)&vl[(tn * 16 + l15) * 72 + kc * 32 + quad * 8];
                y[tn] = MFMA16(pa, vb8, y[tn]);
            }
        }
    }
    // reduce den across the 16 lanes of each quad-group
#pragma unroll
    for (int m = 1; m < 16; m <<= 1) {
#pragma unroll
        for (int r = 0; r < 4; r++) den[r] += __shfl_xor(den[r], m);
    }
    const int rowb = b * SEQ + q0 + wave * 16 + quad * 4;
    size_t ybase = (size_t)split * BS * DD + (size_t)rowb * DD;
#pragma unroll
    for (int tn = 0; tn < 4; tn++) {
#pragma unroll
        for (int r = 0; r < 4; r++) {
            Yp[ybase + (size_t)r * DD + tn * 16 + l15] = f2bf(y[tn][r]);
        }
    }
    if (l15 == 0) {
#pragma unroll
        for (int r = 0; r < 4; r++) Dp[split * BS + rowb + r] = den[r];
    }
}

// ---------------------------------------------------------------------------
// Kernel 5: combine splits + reverse transform + LayerNorm. One wave per
// q-row (lane = v), fully coalesced.
// ---------------------------------------------------------------------------
__global__ __launch_bounds__(256) void reduce_ln_kernel(
        const short* __restrict__ Yp, const float* __restrict__ Dp,
        const float* __restrict__ C, const float* __restrict__ gamma,
        const float* __restrict__ beta, float* __restrict__ out) {
    const int row = blockIdx.x * 4 + (threadIdx.x >> 6);
    const int v = threadIdx.x & 63;
    const int b = row >> 11;
    float Y = 0.f, D = 0.f;
#pragma unroll
    for (int s = 0; s < NSPLIT; s++) {
        Y += bf2f(Yp[((size_t)s * BS + row) * DD + v]);
        D += Dp[s * BS + row];
    }
    float attn = (C[b * DD + v] - Y / D) * (1.0f / (float)(SEQ - 1));
    float msum = attn, ssum = attn * attn;
#pragma unroll
    for (int m = 1; m < 64; m <<= 1) {
        msum += __shfl_xor(msum, m);
        ssum += __shfl_xor(ssum, m);
    }
    float mu = msum * (1.0f / 64.0f);
    float var = ssum * (1.0f / 64.0f) - mu * mu;
    float rs = rsqrtf(var + 1e-5f);
    out[(size_t)row * DD + v] = (attn - mu) * rs * gamma[v] + beta[v];
}

// ---------------------------------------------------------------------------
extern "C" void kernel_launch(void* const* d_in, const int* in_sizes, int n_in,
                              void* d_out, int out_size, void* d_ws, size_t ws_size,
                              hipStream_t stream) {
    const float* x1    = (const float*)d_in[0];
    const float* x2    = (const float*)d_in[1];
    const float* Wq    = (const float*)d_in[2];
    const float* bq    = (const float*)d_in[3];
    const float* Wk    = (const float*)d_in[4];
    const float* bk    = (const float*)d_in[5];
    const float* Wv    = (const float*)d_in[6];
    const float* bv    = (const float*)d_in[7];
    const float* gamma = (const float*)d_in[8];
    const float* beta  = (const float*)d_in[9];
    float* out = (float*)d_out;

    char* ws = (char*)d_ws;
    short* Qs  = (short*)(ws);                         // 2 MB  bf16 [16384][64] (pre-scaled)
    short* Kb  = (short*)(ws + (2ull << 20));          // 2 MB  bf16 [16384][64]
    short* Vtb = (short*)(ws + (4ull << 20));          // 2 MB  bf16 [8][64][2048]
    short* Wt  = (short*)(ws + (6ull << 20));          // 288 KB bf16 [3][64][768]
    float* Cc  = (float*)(ws + (6ull << 20) + 3 * DM * DD * 2);  // 2 KB f32 [8][64]
    short* Yp  = (short*)(ws + (7ull << 20));          // 8 MB  bf16 [4][16384][64]
    float* Dp  = (float*)(ws + (16ull << 20));         // 256 KB f32 [4][16384]

    prep_w_kernel<<<576, 256, 0, stream>>>(Wq, Wk, Wv, Wt);
    fused_proj_kernel<<<2048, 64, 0, stream>>>(x1, x2, Wt, bq, bk, bv, Qs, Kb, Vtb);
    csum_kernel<<<512, 64, 0, stream>>>(Vtb, Cc);
    flash_kernel<<<dim3(32, 8, NSPLIT), 256, 0, stream>>>(Qs, Kb, Vtb, Yp, Dp);
    reduce_ln_kernel<<<BS / 4, 256, 0, stream>>>(Yp, Dp, Cc, gamma, beta, out);
}

// Round 3
// 199.474 us; speedup vs baseline: 1.1478x; 1.1340x over previous
//
#include <hip/hip_runtime.h>
#include <hip/hip_bf16.h>

// Shapes (fixed by the problem)
#define BATCH 8
#define SEQ   2048
#define DM    768
#define DD    64   // DK == DV == 64
#define NSPLIT 4
#define SPLIT_S (SEQ / NSPLIT)   // 512
#define BS (BATCH * SEQ)         // 16384

typedef __bf16 bf16x8 __attribute__((ext_vector_type(8)));
typedef float  f32x4  __attribute__((ext_vector_type(4)));
typedef short  short8 __attribute__((ext_vector_type(8)));
typedef short  short4v __attribute__((ext_vector_type(4)));

#define MFMA16(a, b, c) __builtin_amdgcn_mfma_f32_16x16x32_bf16((a), (b), (c), 0, 0, 0)

__device__ __forceinline__ short f2bf(float x) {
    unsigned u = __builtin_bit_cast(unsigned, x);
    u = (u + 0x7fffu + ((u >> 16) & 1u)) >> 16;   // round-to-nearest-even
    return (short)u;
}
__device__ __forceinline__ float bf2f(short s) {
    unsigned u = ((unsigned)(unsigned short)s) << 16;
    return __builtin_bit_cast(float, u);
}

// ---------------------------------------------------------------------------
// Kernel 1: W [768][64] f32 -> Wt [3][64][768] bf16 (transposed, n-major).
// Wq pre-scaled by 1/8 (the 1/sqrt(DK) of the scores).
// ---------------------------------------------------------------------------
__global__ void prep_w_kernel(const float* __restrict__ Wq, const float* __restrict__ Wk,
                              const float* __restrict__ Wv, short* __restrict__ Wt) {
    int idx = blockIdx.x * 256 + threadIdx.x;
    if (idx >= 3 * DM * DD) return;
    int m = idx / (DM * DD);
    int r = (idx % (DM * DD)) / DD;
    int c = idx % DD;
    const float* W = (m == 0) ? Wq : (m == 1) ? Wk : Wv;
    float scale = (m == 0) ? 0.125f : 1.0f;
    Wt[m * DM * DD + c * DM + r] = f2bf(W[r * DD + c] * scale);
}

// ---------------------------------------------------------------------------
// Kernel 2: projections, 1 wave/block, 16 rows/wave, prefetch-pipelined.
// blocks [0,1024): Q = (x1@Wq + bq)/8      -> Qs row-major
// blocks [1024,2048): K = x2@Wk + bk      -> Kb row-major
// blocks [2048,3072): V = x2@Wv + bv      -> Vtb transposed [b][v][s],
//                     + fused column-sum C[b][v] via f32 atomics.
// ---------------------------------------------------------------------------
__global__ __launch_bounds__(64, 4) void proj_kernel(
        const float* __restrict__ x1, const float* __restrict__ x2,
        const short* __restrict__ Wt,
        const float* __restrict__ bq, const float* __restrict__ bk,
        const float* __restrict__ bv,
        short* __restrict__ Qs, short* __restrict__ Kb, short* __restrict__ Vtb,
        float* __restrict__ C) {
    const int lane = threadIdx.x, quad = lane >> 4, l15 = lane & 15;
    const int m  = blockIdx.x >> 10;          // 0=Q, 1=K, 2=V
    const int r0 = (blockIdx.x & 1023) * 16;

    const float* xp = ((m == 0) ? x1 : x2) + (size_t)(r0 + l15) * DM + quad * 8;
    const short* wp = Wt + (size_t)m * DM * DD + (size_t)l15 * DM + quad * 8;

    f32x4 acc[4] = {};
    float4 ca = *(const float4*)xp;
    float4 cb = *(const float4*)(xp + 4);
    bf16x8 w0 = *(const bf16x8*)(wp);
    bf16x8 w1 = *(const bf16x8*)(wp + 16 * DM);
    bf16x8 w2 = *(const bf16x8*)(wp + 32 * DM);
    bf16x8 w3 = *(const bf16x8*)(wp + 48 * DM);
#pragma unroll
    for (int k0 = 0; k0 < DM; k0 += 32) {
        float4 na, nb; bf16x8 n0, n1, n2, n3;
        if (k0 + 32 < DM) {
            na = *(const float4*)(xp + k0 + 32);
            nb = *(const float4*)(xp + k0 + 36);
            n0 = *(const bf16x8*)(wp + k0 + 32);
            n1 = *(const bf16x8*)(wp + 16 * DM + k0 + 32);
            n2 = *(const bf16x8*)(wp + 32 * DM + k0 + 32);
            n3 = *(const bf16x8*)(wp + 48 * DM + k0 + 32);
        }
        bf16x8 af;
        af[0] = (__bf16)ca.x; af[1] = (__bf16)ca.y; af[2] = (__bf16)ca.z; af[3] = (__bf16)ca.w;
        af[4] = (__bf16)cb.x; af[5] = (__bf16)cb.y; af[6] = (__bf16)cb.z; af[7] = (__bf16)cb.w;
        acc[0] = MFMA16(af, w0, acc[0]);
        acc[1] = MFMA16(af, w1, acc[1]);
        acc[2] = MFMA16(af, w2, acc[2]);
        acc[3] = MFMA16(af, w3, acc[3]);
        ca = na; cb = nb; w0 = n0; w1 = n1; w2 = n2; w3 = n3;
    }

    if (m == 0) {
#pragma unroll
        for (int tn = 0; tn < 4; tn++) {
            int v = tn * 16 + l15;
            float bb = bq[v] * 0.125f;
#pragma unroll
            for (int r = 0; r < 4; r++)
                Qs[(size_t)(r0 + quad * 4 + r) * DD + v] = f2bf(acc[tn][r] + bb);
        }
    } else if (m == 1) {
#pragma unroll
        for (int tn = 0; tn < 4; tn++) {
            int v = tn * 16 + l15;
            float bb = bk[v];
#pragma unroll
            for (int r = 0; r < 4; r++)
                Kb[(size_t)(r0 + quad * 4 + r) * DD + v] = f2bf(acc[tn][r] + bb);
        }
    } else {
        const int b = r0 / SEQ;
        const int sbase = (r0 % SEQ) + quad * 4;
#pragma unroll
        for (int tn = 0; tn < 4; tn++) {
            int v = tn * 16 + l15;
            float bb = bv[v];
            short4v pk;
            float cs = 0.f;
#pragma unroll
            for (int r = 0; r < 4; r++) {
                pk[r] = f2bf(acc[tn][r] + bb);
                cs += bf2f(pk[r]);           // sum the rounded values (consistency)
            }
            *(short4v*)(Vtb + ((size_t)b * DD + v) * SEQ + sbase) = pk;
            cs += __shfl_xor(cs, 16);
            cs += __shfl_xor(cs, 32);
            if (quad == 0) atomicAdd(&C[b * DD + v], cs);
        }
    }
}

// ---------------------------------------------------------------------------
// Kernel 3: flash partial, transposed-score formulation.
// grid (32 q-tiles, 8 batches, NSPLIT). Z^T = K.Q^T (A=K-frag, B=Q-frag);
// C-layout gives q=l15, s=tn*16+quad*4+r -> 4 consecutive s per reg-quad,
// so P^T -> LDS is 4x ds_write_b64; PV B-frags read back as b128.
// Y^T = V^T.P^T: q=l15, v=tn*16+quad*4+r. Emits unnormalized Yp + den Dp.
// ---------------------------------------------------------------------------
#define KSTR 80   // kl/vl row stride (shorts): 160B, 16B-aligned, 4-way max
#define PSTR 72   // pb row stride (shorts): 144B, b64 writes 2-way (free)
__global__ __launch_bounds__(256) void flash_kernel(
        const short* __restrict__ Q, const short* __restrict__ K,
        const short* __restrict__ Vt,
        short* __restrict__ Yp, float* __restrict__ Dp) {
    __shared__ __align__(16) short kl[64 * KSTR];     // K tile [s][d]
    __shared__ __align__(16) short vl[64 * KSTR];     // Vt tile [v][s]
    __shared__ __align__(16) short pb[4][16 * PSTR];  // per-wave P^T [q][s]
    const int tid  = threadIdx.x;
    const int wave = tid >> 6, lane = tid & 63, quad = lane >> 4, l15 = lane & 15;
    const int b = blockIdx.y, q0 = blockIdx.x * 64, split = blockIdx.z;

    // Q as B-operand: n=l15 -> q-row = q0+wave*16+l15; k = d = quad*8+j
    const short* Qp = Q + ((size_t)(b * SEQ + q0) + wave * 16 + l15) * DD;
    bf16x8 qb0 = *(const bf16x8*)(Qp + quad * 8);
    bf16x8 qb1 = *(const bf16x8*)(Qp + 32 + quad * 8);

    const short* Kb = K  + (size_t)b * SEQ * DD;
    const short* Vb = Vt + (size_t)b * DD * SEQ;
    f32x4 y[4] = {};
    float den = 0.f;
    const int trow = tid >> 2, tcb = (tid & 3) * 2;
    short* pw = &pb[wave][0];

    const int send = split * SPLIT_S + SPLIT_S;
    for (int s0 = split * SPLIT_S; s0 < send; s0 += 64) {
        __syncthreads();
        const short* kp = Kb + (size_t)(s0 + trow) * DD + tcb * 8;
        *(short8*)&kl[trow * KSTR + tcb * 8]     = *(const short8*)kp;
        *(short8*)&kl[trow * KSTR + tcb * 8 + 8] = *(const short8*)(kp + 8);
        const short* vp = Vb + (size_t)trow * SEQ + s0 + tcb * 8;
        *(short8*)&vl[trow * KSTR + tcb * 8]     = *(const short8*)vp;
        *(short8*)&vl[trow * KSTR + tcb * 8 + 8] = *(const short8*)(vp + 8);
        __syncthreads();
        // Z^T = K.Q^T: per tn-subtile (s = tn*16+l15)
#pragma unroll
        for (int tn = 0; tn < 4; tn++) {
            bf16x8 ka0 = *(const bf16x8*)&kl[(tn * 16 + l15) * KSTR + quad * 8];
            bf16x8 ka1 = *(const bf16x8*)&kl[(tn * 16 + l15) * KSTR + 32 + quad * 8];
            f32x4 z = {0.f, 0.f, 0.f, 0.f};
            z = MFMA16(ka0, qb0, z);
            z = MFMA16(ka1, qb1, z);
            // exp + den + pack 4 consecutive s -> one b64 LDS write
            short4v pk;
#pragma unroll
            for (int r = 0; r < 4; r++) {
                float p = __expf(z[r]);
                den += p;
                pk[r] = f2bf(p);
            }
            *(short4v*)&pw[l15 * PSTR + tn * 16 + quad * 4] = pk;
        }
        // Y^T += V^T.P^T: A = V^T frag, B = P^T frag [k=s][n=q]
#pragma unroll
        for (int kc = 0; kc < 2; kc++) {
            bf16x8 pB = *(const bf16x8*)&pw[l15 * PSTR + kc * 32 + quad * 8];
#pragma unroll
            for (int tn = 0; tn < 4; tn++) {
                bf16x8 va = *(const bf16x8*)&vl[(tn * 16 + l15) * KSTR + kc * 32 + quad * 8];
                y[tn] = MFMA16(va, pB, y[tn]);
            }
        }
    }
    // den: sum partial s-subsets across the 4 quads sharing q=l15
    den += __shfl_xor(den, 16);
    den += __shfl_xor(den, 32);
    const int qrow = b * SEQ + q0 + wave * 16 + l15;
    size_t ybase = (size_t)split * BS * DD + (size_t)qrow * DD;
#pragma unroll
    for (int tn = 0; tn < 4; tn++) {
        short4v pk;
#pragma unroll
        for (int r = 0; r < 4; r++) pk[r] = f2bf(y[tn][r]);
        *(short4v*)(Yp + ybase + tn * 16 + quad * 4) = pk;
    }
    if (quad == 0) Dp[split * BS + qrow] = den;
}

// ---------------------------------------------------------------------------
// Kernel 4: combine splits + reverse transform + LayerNorm. One wave/q-row.
// ---------------------------------------------------------------------------
__global__ __launch_bounds__(256) void reduce_ln_kernel(
        const short* __restrict__ Yp, const float* __restrict__ Dp,
        const float* __restrict__ C, const float* __restrict__ gamma,
        const float* __restrict__ beta, float* __restrict__ out) {
    const int row = blockIdx.x * 4 + (threadIdx.x >> 6);
    const int v = threadIdx.x & 63;
    const int b = row >> 11;
    float Y = 0.f, D = 0.f;
#pragma unroll
    for (int s = 0; s < NSPLIT; s++) {
        Y += bf2f(Yp[((size_t)s * BS + row) * DD + v]);
        D += Dp[s * BS + row];
    }
    float attn = (C[b * DD + v] - Y / D) * (1.0f / (float)(SEQ - 1));
    float msum = attn, ssum = attn * attn;
#pragma unroll
    for (int m = 1; m < 64; m <<= 1) {
        msum += __shfl_xor(msum, m);
        ssum += __shfl_xor(ssum, m);
    }
    float mu = msum * (1.0f / 64.0f);
    float var = ssum * (1.0f / 64.0f) - mu * mu;
    float rs = rsqrtf(var + 1e-5f);
    out[(size_t)row * DD + v] = (attn - mu) * rs * gamma[v] + beta[v];
}

// ---------------------------------------------------------------------------
extern "C" void kernel_launch(void* const* d_in, const int* in_sizes, int n_in,
                              void* d_out, int out_size, void* d_ws, size_t ws_size,
                              hipStream_t stream) {
    const float* x1    = (const float*)d_in[0];
    const float* x2    = (const float*)d_in[1];
    const float* Wq    = (const float*)d_in[2];
    const float* bq    = (const float*)d_in[3];
    const float* Wk    = (const float*)d_in[4];
    const float* bk    = (const float*)d_in[5];
    const float* Wv    = (const float*)d_in[6];
    const float* bv    = (const float*)d_in[7];
    const float* gamma = (const float*)d_in[8];
    const float* beta  = (const float*)d_in[9];
    float* out = (float*)d_out;

    char* ws = (char*)d_ws;
    short* Qs  = (short*)(ws);                         // 2 MB  bf16 [16384][64]
    short* Kb  = (short*)(ws + (2ull << 20));          // 2 MB  bf16 [16384][64]
    short* Vtb = (short*)(ws + (4ull << 20));          // 2 MB  bf16 [8][64][2048]
    short* Wt  = (short*)(ws + (6ull << 20));          // 288 KB bf16 [3][64][768]
    float* Cc  = (float*)(ws + (6ull << 20) + 3 * DM * DD * 2);  // 2 KB f32 [8][64]
    short* Yp  = (short*)(ws + (7ull << 20));          // 8 MB  bf16 [NSPLIT][16384][64]
    float* Dp  = (float*)(ws + (16ull << 20));         // 256 KB f32 [NSPLIT][16384]

    hipMemsetAsync(Cc, 0, BATCH * DD * sizeof(float), stream);
    prep_w_kernel<<<576, 256, 0, stream>>>(Wq, Wk, Wv, Wt);
    proj_kernel<<<3072, 64, 0, stream>>>(x1, x2, Wt, bq, bk, bv, Qs, Kb, Vtb, Cc);
    flash_kernel<<<dim3(32, 8, NSPLIT), 256, 0, stream>>>(Qs, Kb, Vtb, Yp, Dp);
    reduce_ln_kernel<<<BS / 4, 256, 0, stream>>>(Yp, Dp, Cc, gamma, beta, out);
}